// Round 14
// baseline (1457.961 us; speedup 1.0000x reference)
//
#include <hip/hip_runtime.h>
#include <hip/hip_fp8.h>
#include <cfloat>

#define N_ROWS 16384
#define DDIM   768
#define KCOLS  10000
#define KPAD   10112   // 79 * 128
#define MARGIN 32.0f   // 8 sigma of fp8-e4m3 score-diff error

#define TRANSC_BLKS (KPAD / 32 * (DDIM / 32))   // 316*24 = 7584
#define CONVX_BLKS  (N_ROWS * 48 / 256)         // 3072  (48 x 16B chunks per row)
#define CNORM_BLKS  (KPAD / 64)                 // 158

typedef __attribute__((ext_vector_type(4))) int i32x4;
typedef __attribute__((ext_vector_type(8))) int i32x8;
typedef __attribute__((ext_vector_type(16))) float f32x16;
typedef unsigned long long u64;
typedef unsigned int u32;

__device__ __forceinline__ u32 fsort(float f) {
  u32 u = __float_as_uint(f);
  return (u & 0x80000000u) ? ~u : (u | 0x80000000u);
}
__device__ __forceinline__ float funsort(u32 u) {
  u32 b = (u & 0x80000000u) ? (u ^ 0x80000000u) : ~u;
  return __uint_as_float(b);
}
__device__ __forceinline__ unsigned char f2q(float f) {   // fp8 e4m3 (OCP), RNE+sat
  return (unsigned char)__hip_cvt_float_to_fp8(f, __HIP_SATFINITE, __HIP_E4M3);
}

// ============================ fused pre-pass ============================
// [0, TRANSC): C [768][10000] -> Cq [10112][768] fp8 (chunk-swizzled) + Ct f32 (linear)
// [TRANSC, +CONVX): X -> Xq fp8 (chunk-swizzled, 16 elems/thread) + init best
// [+CONVX, +CNORM): centroid norms (fixed-order reduce)
__global__ __launch_bounds__(256) void prep_kernel(
    const float* __restrict__ X, const float* __restrict__ C,
    unsigned char* __restrict__ Xq, unsigned char* __restrict__ Cq,
    float* __restrict__ Ct, float* __restrict__ cn, u64* __restrict__ best) {
  __shared__ float smem[32 * 33];
  const int bid = blockIdx.x;
  const int t = threadIdx.x;

  if (bid < TRANSC_BLKS) {
    const int kk = (bid % (KPAD / 32)) * 32;
    const int dd = (bid / (KPAD / 32)) * 32;
    const int tx = t & 31, ty = t >> 5;
#pragma unroll
    for (int j = 0; j < 4; ++j) {
      int d = dd + ty + j * 8, k = kk + tx;
      smem[(ty + j * 8) * 33 + tx] = (k < KCOLS) ? C[(size_t)d * KCOLS + k] : 0.f;
    }
    __syncthreads();
#pragma unroll
    for (int j = 0; j < 4; ++j) {
      int k = kk + ty + j * 8, d = dd + tx;
      float v = smem[tx * 33 + (ty + j * 8)];
      // chunk-swizzle: 16B chunks, 8 per 128B K-tile, key = k&7
      int swz = (d & ~127) + ((((d >> 4) & 7) ^ (k & 7)) << 4) + (d & 15);
      Cq[(size_t)k * DDIM + swz] = f2q(v);
      Ct[(size_t)k * DDIM + d] = v;
    }
  } else if (bid < TRANSC_BLKS + CONVX_BLKS) {
    int i = (bid - TRANSC_BLKS) * 256 + t;    // 16-byte output chunk index
    if (i < N_ROWS) best[i] = ~0ULL;
    int row = i / 48;
    int pc  = i % 48;                          // physical chunk
    int lc  = (pc & ~7) | ((pc & 7) ^ (row & 7));
    const float4* p = (const float4*)(X + (size_t)row * DDIM + lc * 16);
    union { unsigned char b[16]; uint4 v; } o;
#pragma unroll
    for (int q = 0; q < 4; ++q) {
      float4 f = p[q];
      o.b[q * 4 + 0] = f2q(f.x); o.b[q * 4 + 1] = f2q(f.y);
      o.b[q * 4 + 2] = f2q(f.z); o.b[q * 4 + 3] = f2q(f.w);
    }
    *((uint4*)Xq + i) = o.v;
  } else {
    const int kb = bid - TRANSC_BLKS - CONVX_BLKS;
    const int tx = t & 63, ty = t >> 6;
    const int k = kb * 64 + tx;
    float s = 0.f;
    if (k < KCOLS) {
      const float* p = C + (size_t)(ty * 192) * KCOLS + k;
      for (int d = 0; d < 192; ++d) {
        float v = p[(size_t)d * KCOLS];
        s = fmaf(v, v, s);
      }
    }
    smem[ty * 64 + tx] = s;
    __syncthreads();
    if (ty == 0)
      cn[k] = (k < KCOLS)
                  ? ((smem[tx] + smem[64 + tx]) + (smem[128 + tx] + smem[192 + tx]))
                  : FLT_MAX;
  }
}

#define GLOAD_LDS16(gp, lp)                                                     \
  __builtin_amdgcn_global_load_lds((const __attribute__((address_space(1))) void*)(gp), \
                                   (__attribute__((address_space(3))) void*)(lp), 16, 0, 0)

#define SCALE1 0x7F7F7F7F   // four E8M0 bytes of 127 = 2^0

// Build an 8-VGPR fp8 fragment: 32 contiguous k-bytes for lane group (l>>5),
// read as two swizzled 16B chunks. BASE = LDS row base (128B rows), key = (l&31)&7.
#define FRAG8(DST, BASE, TT, LG, KEY) do {                                        \
  const int _c0 = (TT) * 4 + (LG) * 2;                                            \
  i32x4 _lo = *(const i32x4*)((BASE) + (((_c0)     ^ (KEY)) * 16));               \
  i32x4 _hi = *(const i32x4*)((BASE) + (((_c0 + 1) ^ (KEY)) * 16));               \
  DST[0]=_lo[0]; DST[1]=_lo[1]; DST[2]=_lo[2]; DST[3]=_lo[3];                     \
  DST[4]=_hi[0]; DST[5]=_hi[1]; DST[6]=_hi[2]; DST[7]=_hi[3];                     \
} while (0)

// ==================== MX-fp8 seed: 128 rows x 64 sampled centroids ====================
// cand j = 0..63, k = j*158. Plain store to amin (single writer), no init needed.
__global__ __launch_bounds__(256) void seed_fp8(
    const unsigned char* __restrict__ Xq, const unsigned char* __restrict__ Cq,
    const float* __restrict__ cn, u32* __restrict__ amin) {
  __shared__ __align__(16) unsigned char As[128 * 128];
  __shared__ __align__(16) unsigned char Bs[64 * 128];

  const int t = threadIdx.x;
  const int lane = t & 63, wave = t >> 6;
  const int n0 = blockIdx.x * 128;
  const int l31 = lane & 31, lg = lane >> 5;
  const int keyA = l31 & 7;
  const int keyB = (l31 * 6) & 7;              // (j*158)&7 with j=n*32+l31; n*32*158%8==0

  f32x16 acc[2];
#pragma unroll
  for (int n = 0; n < 2; ++n)
#pragma unroll
    for (int r = 0; r < 16; ++r) acc[n][r] = 0.f;

  for (int it = 0; it < 6; ++it) {
#pragma unroll
    for (int i = 0; i < 4; ++i)
      GLOAD_LDS16(Xq + (size_t)(n0 + wave * 32 + i * 8 + (lane >> 3)) * DDIM + it * 128 + (lane & 7) * 16,
                  As + (wave * 32 + i * 8) * 128);
#pragma unroll
    for (int i = 0; i < 2; ++i)
      GLOAD_LDS16(Cq + (size_t)(wave * 16 + i * 8 + (lane >> 3)) * 158 * DDIM + it * 128 + (lane & 7) * 16,
                  Bs + (wave * 16 + i * 8) * 128);
    __syncthreads();
#pragma unroll
    for (int tt = 0; tt < 2; ++tt) {
      i32x8 av, bv0, bv1;
      FRAG8(av,  As + (wave * 32 + l31) * 128, tt, lg, keyA);
      FRAG8(bv0, Bs + (l31) * 128,             tt, lg, keyB);
      FRAG8(bv1, Bs + (32 + l31) * 128,        tt, lg, keyB);
      acc[0] = __builtin_amdgcn_mfma_scale_f32_32x32x64_f8f6f4(
          av, bv0, acc[0], 0, 0, 0, SCALE1, 0, SCALE1);
      acc[1] = __builtin_amdgcn_mfma_scale_f32_32x32x64_f8f6f4(
          av, bv1, acc[1], 0, 0, 0, SCALE1, 0, SCALE1);
    }
    __syncthreads();
  }

  float cnv[2];
#pragma unroll
  for (int n = 0; n < 2; ++n) cnv[n] = cn[(n * 32 + l31) * 158];

#pragma unroll
  for (int reg = 0; reg < 16; ++reg) {
    float s0 = fmaf(-2.f, acc[0][reg], cnv[0]);
    float s1 = fmaf(-2.f, acc[1][reg], cnv[1]);
    float v = fminf(s0, s1);
#pragma unroll
    for (int s = 1; s < 32; s <<= 1) v = fminf(v, __shfl_xor(v, s));  // within 32-half
    int row = n0 + wave * 32 + (reg & 3) + 8 * (reg >> 2) + 4 * lg;
    if (l31 == 0) amin[row] = fsort(v);
  }
}

// ============ MX-fp8 fused GEMM + argmin: 128x128 tile, 4 waves (2x2) ============
__global__ __launch_bounds__(256, 4) void assign_fp8(
    const unsigned char* __restrict__ Xq, const unsigned char* __restrict__ Cq,
    const float* __restrict__ X32, const float* __restrict__ Ct,
    const float* __restrict__ cn, u32* __restrict__ amin, u64* __restrict__ best) {
  __shared__ __align__(16) unsigned char As[128 * 128];   // [row][K=128 fp8, swizzled]
  __shared__ __align__(16) unsigned char Bs[128 * 128];

  const int t = threadIdx.x;
  const int lane = t & 63, wave = t >> 6;
  const int wr = wave >> 1, wc = wave & 1;     // 2x2 waves, per-wave 64x64
  const int n0 = blockIdx.x * 128;
  const int k0 = blockIdx.y * 128;
  const int l31 = lane & 31, lg = lane >> 5;
  const int key = l31 & 7;

  f32x16 acc[2][2];
#pragma unroll
  for (int m = 0; m < 2; ++m)
#pragma unroll
    for (int n = 0; n < 2; ++n)
#pragma unroll
      for (int r = 0; r < 16; ++r) acc[m][n][r] = 0.f;

  for (int it = 0; it < 6; ++it) {
#pragma unroll
    for (int i = 0; i < 4; ++i) {
      GLOAD_LDS16(Xq + (size_t)(n0 + wave * 32 + i * 8 + (lane >> 3)) * DDIM + it * 128 + (lane & 7) * 16,
                  As + (wave * 32 + i * 8) * 128);
      GLOAD_LDS16(Cq + (size_t)(k0 + wave * 32 + i * 8 + (lane >> 3)) * DDIM + it * 128 + (lane & 7) * 16,
                  Bs + (wave * 32 + i * 8) * 128);
    }
    __syncthreads();
#pragma unroll
    for (int tt = 0; tt < 2; ++tt) {
      i32x8 a0, a1, b0, b1;
      FRAG8(a0, As + (wr * 64 + l31) * 128,      tt, lg, key);
      FRAG8(a1, As + (wr * 64 + 32 + l31) * 128, tt, lg, key);
      FRAG8(b0, Bs + (wc * 64 + l31) * 128,      tt, lg, key);
      FRAG8(b1, Bs + (wc * 64 + 32 + l31) * 128, tt, lg, key);
      acc[0][0] = __builtin_amdgcn_mfma_scale_f32_32x32x64_f8f6f4(a0, b0, acc[0][0], 0, 0, 0, SCALE1, 0, SCALE1);
      acc[0][1] = __builtin_amdgcn_mfma_scale_f32_32x32x64_f8f6f4(a0, b1, acc[0][1], 0, 0, 0, SCALE1, 0, SCALE1);
      acc[1][0] = __builtin_amdgcn_mfma_scale_f32_32x32x64_f8f6f4(a1, b0, acc[1][0], 0, 0, 0, SCALE1, 0, SCALE1);
      acc[1][1] = __builtin_amdgcn_mfma_scale_f32_32x32x64_f8f6f4(a1, b1, acc[1][1], 0, 0, 0, SCALE1, 0, SCALE1);
    }
    __syncthreads();
  }

  // ---------------- epilogue: approx min + exact rescore ----------------
  float cnv[2];
#pragma unroll
  for (int n = 0; n < 2; ++n) cnv[n] = cn[k0 + wc * 64 + n * 32 + l31];

#pragma unroll
  for (int m = 0; m < 2; ++m) {
#pragma unroll
    for (int reg = 0; reg < 16; ++reg) {
      float s0 = fmaf(-2.f, acc[m][0][reg], cnv[0]);
      float s1 = fmaf(-2.f, acc[m][1][reg], cnv[1]);
      float v = fminf(s0, s1);
#pragma unroll
      for (int s = 1; s < 32; s <<= 1) v = fminf(v, __shfl_xor(v, s));  // 32-half
      const int rbase = (reg & 3) + 8 * (reg >> 2);
      int row = n0 + wr * 64 + m * 32 + rbase + 4 * lg;
      u32 kk = fsort(v);
      u32 mr = kk;
      if (l31 == 0) {
        u32 old = atomicMin(&amin[row], kk);
        mr = old < kk ? old : kk;
      }
      mr = __shfl(mr, lane & 32);              // broadcast from lane 0 / 32
      float th = funsort(mr) + MARGIN;

#pragma unroll
      for (int n = 0; n < 2; ++n) {
        float scn = (n == 0) ? s0 : s1;
        int kq = k0 + wc * 64 + n * 32 + l31;
        bool cand = (kq < KCOLS) && (scn <= th);
        u64 mask = __ballot(cand);
        while (mask) {
          int src = (int)__builtin_ctzll(mask);
          mask &= mask - 1;
          int srowg = n0 + wr * 64 + m * 32 + rbase + 4 * (src >> 5);
          int skg = k0 + wc * 64 + n * 32 + (src & 31);
          float part = 0.f;
          const float* xp = X32 + (size_t)srowg * DDIM + lane;
          const float* cp = Ct + (size_t)skg * DDIM + lane;   // coalesced
#pragma unroll
          for (int ii = 0; ii < 12; ++ii)
            part = fmaf(xp[ii * 64], cp[ii * 64], part);
#pragma unroll
          for (int s = 1; s < 64; s <<= 1) part += __shfl_xor(part, s);
          if (lane == 0) {
            float ex = fmaf(-2.f, part, cn[skg]);
            atomicMin(&best[srowg], ((u64)fsort(ex) << 32) | (u32)skg);
          }
        }
      }
    }
  }
}

// ============================ fp32 fallback path ============================

__global__ void cnorm_kernel(const float* __restrict__ C, float* __restrict__ cnorm,
                             int D, int K) {
  int k = blockIdx.x * blockDim.x + threadIdx.x;
  if (k >= K) return;
  float s = 0.f;
  for (int d = 0; d < D; ++d) {
    float v = C[(size_t)d * K + k];
    s = fmaf(v, v, s);
  }
  cnorm[k] = s;
}

__global__ void init_kernel(u64* best, int N) {
  int n = blockIdx.x * blockDim.x + threadIdx.x;
  if (n < N) best[n] = ~0ULL;
}

__device__ __forceinline__ u32 fsort2(float f) { return fsort(f); }

__global__ __launch_bounds__(256) void assign_kernel(
    const float* __restrict__ X, const float* __restrict__ C,
    const float* __restrict__ cnorm, u64* __restrict__ best,
    int N, int D, int K) {
  __shared__ float Xs[16][128];
  __shared__ float Cs[16][64];
  const int t = threadIdx.x;
  const int tx = t & 15, ty = t >> 4;
  const int k0 = blockIdx.x * 64;
  const int n0 = blockIdx.y * 128;
  float acc[8][4];
#pragma unroll
  for (int i = 0; i < 8; ++i)
#pragma unroll
    for (int j = 0; j < 4; ++j) acc[i][j] = 0.f;
  for (int d0 = 0; d0 < D; d0 += 16) {
#pragma unroll
    for (int v = 0; v < 2; ++v) {
      int f4 = t + v * 256;
      int row = f4 >> 2;
      int dc = (f4 & 3) * 4;
      const float4 xv = *(const float4*)&X[(size_t)(n0 + row) * D + d0 + dc];
      Xs[dc + 0][row] = xv.x; Xs[dc + 1][row] = xv.y;
      Xs[dc + 2][row] = xv.z; Xs[dc + 3][row] = xv.w;
    }
    {
      int d = t >> 4, kc = (t & 15) * 4, k = k0 + kc;
      float4 cv;
      if (k + 3 < K) cv = *(const float4*)&C[(size_t)(d0 + d) * K + k];
      else {
        cv.x = (k + 0 < K) ? C[(size_t)(d0 + d) * K + k + 0] : 0.f;
        cv.y = (k + 1 < K) ? C[(size_t)(d0 + d) * K + k + 1] : 0.f;
        cv.z = (k + 2 < K) ? C[(size_t)(d0 + d) * K + k + 2] : 0.f;
        cv.w = (k + 3 < K) ? C[(size_t)(d0 + d) * K + k + 3] : 0.f;
      }
      *(float4*)&Cs[d][kc] = cv;
    }
    __syncthreads();
#pragma unroll
    for (int d = 0; d < 16; ++d) {
      float4 a0 = *(const float4*)&Xs[d][ty * 8];
      float4 a1 = *(const float4*)&Xs[d][ty * 8 + 4];
      float4 b = *(const float4*)&Cs[d][tx * 4];
      float av[8] = {a0.x, a0.y, a0.z, a0.w, a1.x, a1.y, a1.z, a1.w};
      float bv[4] = {b.x, b.y, b.z, b.w};
#pragma unroll
      for (int i = 0; i < 8; ++i)
#pragma unroll
        for (int j = 0; j < 4; ++j) acc[i][j] = fmaf(av[i], bv[j], acc[i][j]);
    }
    __syncthreads();
  }
  float cnv[4];
#pragma unroll
  for (int j = 0; j < 4; ++j) {
    int k = k0 + tx * 4 + j;
    cnv[j] = (k < K) ? cnorm[k] : 0.f;
  }
#pragma unroll
  for (int i = 0; i < 8; ++i) {
    u64 key = ~0ULL;
#pragma unroll
    for (int j = 0; j < 4; ++j) {
      int k = k0 + tx * 4 + j;
      if (k < K) {
        float score = fmaf(-2.f, acc[i][j], cnv[j]);
        u64 cand = ((u64)fsort2(score) << 32) | (unsigned)k;
        key = key < cand ? key : cand;
      }
    }
#pragma unroll
    for (int mk = 8; mk >= 1; mk >>= 1) {
      u64 other = __shfl_xor(key, mk, 16);
      key = key < other ? key : other;
    }
    if (tx == 0) atomicMin(&best[n0 + ty * 8 + i], key);
  }
}

// ---------------- shared output kernel ----------------
__global__ void out_kernel(const u64* __restrict__ best, int* __restrict__ out, int N) {
  int n = blockIdx.x * blockDim.x + threadIdx.x;
  if (n < N) out[n] = (int)(u32)(best[n] & 0xffffffffu);
}

extern "C" void kernel_launch(void* const* d_in, const int* in_sizes, int n_in,
                              void* d_out, int out_size, void* d_ws, size_t ws_size,
                              hipStream_t stream) {
  const float* X = (const float*)d_in[0];  // [N, D]
  const float* C = (const float*)d_in[1];  // [D, K]
  int* out = (int*)d_out;

  // ws layout: best | amin | cnorm | Xq | Cq | Ct
  const size_t OFF_BEST = 0;
  const size_t OFF_AMIN = 131072;
  const size_t OFF_CN   = 196608;
  const size_t OFF_XQ   = 262144;
  const size_t OFF_CQ   = OFF_XQ + (size_t)N_ROWS * DDIM;         // 12845056
  const size_t OFF_CT   = OFF_CQ + (size_t)KPAD * DDIM;           // 20611072
  const size_t REQ_A    = OFF_CT + (size_t)KPAD * DDIM * 4;       // 51675136

  if (ws_size >= REQ_A) {
    u64* best = (u64*)((char*)d_ws + OFF_BEST);
    u32* amin = (u32*)((char*)d_ws + OFF_AMIN);
    float* cnp = (float*)((char*)d_ws + OFF_CN);
    unsigned char* Xq = (unsigned char*)((char*)d_ws + OFF_XQ);
    unsigned char* Cq = (unsigned char*)((char*)d_ws + OFF_CQ);
    float* Ct = (float*)((char*)d_ws + OFF_CT);

    hipLaunchKernelGGL(prep_kernel, dim3(TRANSC_BLKS + CONVX_BLKS + CNORM_BLKS), dim3(256),
                       0, stream, X, C, Xq, Cq, Ct, cnp, best);
    hipLaunchKernelGGL(seed_fp8, dim3(N_ROWS / 128), dim3(256), 0, stream, Xq, Cq, cnp, amin);
    hipLaunchKernelGGL(assign_fp8, dim3(N_ROWS / 128, KPAD / 128), dim3(256), 0, stream,
                       Xq, Cq, X, Ct, cnp, amin, best);
    hipLaunchKernelGGL(out_kernel, dim3(64), dim3(256), 0, stream, best, out, N_ROWS);
  } else {
    // fp32 fallback (round-2 passing path)
    u64* best = (u64*)d_ws;
    float* cnorm = (float*)((char*)d_ws + (size_t)N_ROWS * sizeof(u64));
    hipLaunchKernelGGL(init_kernel, dim3(64), dim3(256), 0, stream, best, N_ROWS);
    hipLaunchKernelGGL(cnorm_kernel, dim3((KCOLS + 255) / 256), dim3(256), 0, stream,
                       C, cnorm, DDIM, KCOLS);
    hipLaunchKernelGGL(assign_kernel, dim3((KCOLS + 63) / 64, N_ROWS / 128), dim3(256), 0,
                       stream, X, C, cnorm, best, N_ROWS, DDIM, KCOLS);
    hipLaunchKernelGGL(out_kernel, dim3(64), dim3(256), 0, stream, best, out, N_ROWS);
  }
}

// Round 15
// 1128.475 us; speedup vs baseline: 1.2920x; 1.2920x over previous
//
#include <hip/hip_runtime.h>
#include <hip/hip_fp8.h>
#include <cfloat>

#define N_ROWS 16384
#define DDIM   768
#define KCOLS  10000
#define KPAD   10112   // 79 * 128
#define MARGIN 32.0f   // 8 sigma of fp8-e4m3 score-diff error

#define TRANSC_BLKS (KPAD / 32 * (DDIM / 32))   // 7584
#define CONVX_BLKS  (N_ROWS * 48 / 256)         // 3072
#define CNORM_BLKS  (KPAD / 64)                 // 158

typedef __attribute__((ext_vector_type(4))) int i32x4;
typedef __attribute__((ext_vector_type(8))) int i32x8;
typedef __attribute__((ext_vector_type(16))) float f32x16;
typedef unsigned long long u64;
typedef unsigned int u32;

__device__ __forceinline__ u32 fsort(float f) {
  u32 u = __float_as_uint(f);
  return (u & 0x80000000u) ? ~u : (u | 0x80000000u);
}
__device__ __forceinline__ float funsort(u32 u) {
  u32 b = (u & 0x80000000u) ? (u ^ 0x80000000u) : ~u;
  return __uint_as_float(b);
}
__device__ __forceinline__ unsigned char f2q(float f) {   // fp8 e4m3 (OCP), RNE+sat
  return (unsigned char)__hip_cvt_float_to_fp8(f, __HIP_SATFINITE, __HIP_E4M3);
}
__device__ __forceinline__ int kf(int r) { return (r ^ (r >> 3)) & 7; }  // swizzle key

// ============================ fused pre-pass ============================
__global__ __launch_bounds__(256) void prep_kernel(
    const float* __restrict__ X, const float* __restrict__ C,
    unsigned char* __restrict__ Xq, unsigned char* __restrict__ Cq,
    float* __restrict__ Ct, float* __restrict__ cn, u64* __restrict__ best) {
  __shared__ float smem[32 * 33];
  const int bid = blockIdx.x;
  const int t = threadIdx.x;

  if (bid < TRANSC_BLKS) {
    const int kk = (bid % (KPAD / 32)) * 32;
    const int dd = (bid / (KPAD / 32)) * 32;
    const int tx = t & 31, ty = t >> 5;
#pragma unroll
    for (int j = 0; j < 4; ++j) {
      int d = dd + ty + j * 8, k = kk + tx;
      smem[(ty + j * 8) * 33 + tx] = (k < KCOLS) ? C[(size_t)d * KCOLS + k] : 0.f;
    }
    __syncthreads();
#pragma unroll
    for (int j = 0; j < 4; ++j) {
      int k = kk + ty + j * 8, d = dd + tx;
      float v = smem[tx * 33 + (ty + j * 8)];
      // 16B-chunk swizzle within each 128B K-tile, key = kf(k)
      int swz = (d & ~127) + ((((d >> 4) & 7) ^ kf(k)) << 4) + (d & 15);
      Cq[(size_t)k * DDIM + swz] = f2q(v);
      Ct[(size_t)k * DDIM + d] = v;
    }
  } else if (bid < TRANSC_BLKS + CONVX_BLKS) {
    int i = (bid - TRANSC_BLKS) * 256 + t;    // 16-byte output chunk index
    if (i < N_ROWS) best[i] = ~0ULL;
    int row = i / 48;
    int pc  = i % 48;
    int lc  = (pc & ~7) | ((pc & 7) ^ kf(row));
    const float4* p = (const float4*)(X + (size_t)row * DDIM + lc * 16);
    union { unsigned char b[16]; uint4 v; } o;
#pragma unroll
    for (int q = 0; q < 4; ++q) {
      float4 f = p[q];
      o.b[q * 4 + 0] = f2q(f.x); o.b[q * 4 + 1] = f2q(f.y);
      o.b[q * 4 + 2] = f2q(f.z); o.b[q * 4 + 3] = f2q(f.w);
    }
    *((uint4*)Xq + i) = o.v;
  } else {
    const int kb = bid - TRANSC_BLKS - CONVX_BLKS;
    const int tx = t & 63, ty = t >> 6;
    const int k = kb * 64 + tx;
    float s = 0.f;
    if (k < KCOLS) {
      const float* p = C + (size_t)(ty * 192) * KCOLS + k;
      for (int d = 0; d < 192; ++d) {
        float v = p[(size_t)d * KCOLS];
        s = fmaf(v, v, s);
      }
    }
    smem[ty * 64 + tx] = s;
    __syncthreads();
    if (ty == 0)
      cn[k] = (k < KCOLS)
                  ? ((smem[tx] + smem[64 + tx]) + (smem[128 + tx] + smem[192 + tx]))
                  : FLT_MAX;
  }
}

#define GLOAD_LDS16(gp, lp)                                                     \
  __builtin_amdgcn_global_load_lds((const __attribute__((address_space(1))) void*)(gp), \
                                   (__attribute__((address_space(3))) void*)(lp), 16, 0, 0)

#define SCALE1 0x7F7F7F7F   // four E8M0 bytes of 127 = 2^0

// 8-VGPR fp8 fragment: 32 contiguous k-bytes (lane k-half LG), two swizzled 16B chunks.
// BASE = LDS row base pointer (128B rows), KEY = kf(row).
#define FRAG8(DST, BASE, TT, LG, KEY) do {                                        \
  const int _c0 = (TT) * 4 + (LG) * 2;                                            \
  i32x4 _lo = *(const i32x4*)((BASE) + (((_c0)     ^ (KEY)) * 16));               \
  i32x4 _hi = *(const i32x4*)((BASE) + (((_c0 + 1) ^ (KEY)) * 16));               \
  DST[0]=_lo[0]; DST[1]=_lo[1]; DST[2]=_lo[2]; DST[3]=_lo[3];                     \
  DST[4]=_hi[0]; DST[5]=_hi[1]; DST[6]=_hi[2]; DST[7]=_hi[3];                     \
} while (0)

// ==================== MX-fp8 seed: 128 rows x 64 sampled centroids ====================
__global__ __launch_bounds__(256) void seed_fp8(
    const unsigned char* __restrict__ Xq, const unsigned char* __restrict__ Cq,
    const float* __restrict__ cn, u32* __restrict__ amin) {
  __shared__ __align__(16) unsigned char As[128 * 128];
  __shared__ __align__(16) unsigned char Bs[64 * 128];

  const int t = threadIdx.x;
  const int lane = t & 63, wave = t >> 6;
  const int n0 = blockIdx.x * 128;
  const int l31 = lane & 31, lg = lane >> 5;
  const int keyA  = kf(wave * 32 + l31);
  const int keyB0 = kf(l31 * 158);             // row j=l31, k=j*158 (stable under +32*158)
  const int keyB1 = kf((l31 + 32) * 158);

  f32x16 acc0, acc1;
#pragma unroll
  for (int r = 0; r < 16; ++r) { acc0[r] = 0.f; acc1[r] = 0.f; }

  for (int it = 0; it < 6; ++it) {
#pragma unroll
    for (int i = 0; i < 4; ++i)
      GLOAD_LDS16(Xq + (size_t)(n0 + wave * 32 + i * 8 + (lane >> 3)) * DDIM + it * 128 + (lane & 7) * 16,
                  As + (wave * 32 + i * 8) * 128);
#pragma unroll
    for (int i = 0; i < 2; ++i)
      GLOAD_LDS16(Cq + (size_t)(wave * 16 + i * 8 + (lane >> 3)) * 158 * DDIM + it * 128 + (lane & 7) * 16,
                  Bs + (wave * 16 + i * 8) * 128);
    __syncthreads();
#pragma unroll
    for (int tt = 0; tt < 2; ++tt) {
      i32x8 av, bv0, bv1;
      FRAG8(av,  As + (wave * 32 + l31) * 128, tt, lg, keyA);
      FRAG8(bv0, Bs + (l31) * 128,             tt, lg, keyB0);
      FRAG8(bv1, Bs + (32 + l31) * 128,        tt, lg, keyB1);
      acc0 = __builtin_amdgcn_mfma_scale_f32_32x32x64_f8f6f4(av, bv0, acc0, 0, 0, 0, SCALE1, 0, SCALE1);
      acc1 = __builtin_amdgcn_mfma_scale_f32_32x32x64_f8f6f4(av, bv1, acc1, 0, 0, 0, SCALE1, 0, SCALE1);
    }
    __syncthreads();
  }

  float cnv0 = cn[l31 * 158];
  float cnv1 = cn[(32 + l31) * 158];

#pragma unroll
  for (int reg = 0; reg < 16; ++reg) {
    float s0 = fmaf(-2.f, acc0[reg], cnv0);
    float s1 = fmaf(-2.f, acc1[reg], cnv1);
    float v = fminf(s0, s1);
#pragma unroll
    for (int s = 1; s < 32; s <<= 1) v = fminf(v, __shfl_xor(v, s));
    int row = n0 + wave * 32 + (reg & 3) + 8 * (reg >> 2) + 4 * lg;
    if (l31 == 0) amin[row] = fsort(v);
  }
}

// ============ MX-fp8 fused GEMM + argmin: 128x128 tile, 4 waves (2x2) ============
#define EPILOG_M(ACCN0, ACCN1, MBASE) do {                                        \
  _Pragma("unroll") for (int reg = 0; reg < 16; ++reg) {                          \
    float s0 = fmaf(-2.f, ACCN0[reg], cnv0);                                      \
    float s1 = fmaf(-2.f, ACCN1[reg], cnv1);                                      \
    float v = fminf(s0, s1);                                                      \
    _Pragma("unroll") for (int s = 1; s < 32; s <<= 1)                            \
      v = fminf(v, __shfl_xor(v, s));                                             \
    const int rbase = (reg & 3) + 8 * (reg >> 2);                                 \
    int row = n0 + wr * 64 + (MBASE) + rbase + 4 * lg;                            \
    u32 kk = fsort(v);                                                            \
    u32 mr = kk;                                                                  \
    if (l31 == 0) {                                                               \
      u32 old = atomicMin(&amin[row], kk);                                        \
      mr = old < kk ? old : kk;                                                   \
    }                                                                             \
    mr = __shfl(mr, lane & 32);                                                   \
    float th = funsort(mr) + MARGIN;                                              \
    _Pragma("unroll") for (int n = 0; n < 2; ++n) {                               \
      float scn = (n == 0) ? s0 : s1;                                             \
      int kq = k0 + wc * 64 + n * 32 + l31;                                       \
      bool cand = (kq < KCOLS) && (scn <= th);                                    \
      u64 mask = __ballot(cand);                                                  \
      while (mask) {                                                              \
        int src = (int)__builtin_ctzll(mask);                                     \
        mask &= mask - 1;                                                         \
        int srowg = n0 + wr * 64 + (MBASE) + rbase + 4 * (src >> 5);              \
        int skg = k0 + wc * 64 + n * 32 + (src & 31);                             \
        float part = 0.f;                                                         \
        const float* xp = X32 + (size_t)srowg * DDIM + lane;                      \
        const float* cp = Ct + (size_t)skg * DDIM + lane;                         \
        _Pragma("unroll") for (int ii = 0; ii < 12; ++ii)                         \
          part = fmaf(xp[ii * 64], cp[ii * 64], part);                            \
        _Pragma("unroll") for (int s = 1; s < 64; s <<= 1)                        \
          part += __shfl_xor(part, s);                                            \
        if (lane == 0) {                                                          \
          float ex = fmaf(-2.f, part, cn[skg]);                                   \
          atomicMin(&best[srowg], ((u64)fsort(ex) << 32) | (u32)skg);             \
        }                                                                         \
      }                                                                           \
    }                                                                             \
  }                                                                               \
} while (0)

__global__ __launch_bounds__(256, 3) void assign_fp8(
    const unsigned char* __restrict__ Xq, const unsigned char* __restrict__ Cq,
    const float* __restrict__ X32, const float* __restrict__ Ct,
    const float* __restrict__ cn, u32* __restrict__ amin, u64* __restrict__ best) {
  __shared__ __align__(16) unsigned char As[128 * 128];   // [row][K=128 fp8, swizzled]
  __shared__ __align__(16) unsigned char Bs[128 * 128];

  const int t = threadIdx.x;
  const int lane = t & 63, wave = t >> 6;
  const int wr = wave >> 1, wc = wave & 1;     // 2x2 waves, per-wave 64x64
  const int n0 = blockIdx.x * 128;
  const int k0 = blockIdx.y * 128;
  const int l31 = lane & 31, lg = lane >> 5;
  const int keyA0 = kf(wr * 64 + l31);         // rows l31 / l31+32 of wave's A block
  const int keyA1 = keyA0 ^ 4;                 // kf(r+32) = kf(r)^4
  const int keyB0 = kf(wc * 64 + l31);
  const int keyB1 = keyB0 ^ 4;

  f32x16 acc00, acc01, acc10, acc11;           // named scalars: cannot be demoted
#pragma unroll
  for (int r = 0; r < 16; ++r) { acc00[r]=0.f; acc01[r]=0.f; acc10[r]=0.f; acc11[r]=0.f; }

  for (int it = 0; it < 6; ++it) {
#pragma unroll
    for (int i = 0; i < 4; ++i) {
      GLOAD_LDS16(Xq + (size_t)(n0 + wave * 32 + i * 8 + (lane >> 3)) * DDIM + it * 128 + (lane & 7) * 16,
                  As + (wave * 32 + i * 8) * 128);
      GLOAD_LDS16(Cq + (size_t)(k0 + wave * 32 + i * 8 + (lane >> 3)) * DDIM + it * 128 + (lane & 7) * 16,
                  Bs + (wave * 32 + i * 8) * 128);
    }
    __syncthreads();
#pragma unroll
    for (int tt = 0; tt < 2; ++tt) {
      i32x8 a0, a1, b0, b1;
      FRAG8(a0, As + (wr * 64 + l31) * 128,      tt, lg, keyA0);
      FRAG8(a1, As + (wr * 64 + 32 + l31) * 128, tt, lg, keyA1);
      FRAG8(b0, Bs + (wc * 64 + l31) * 128,      tt, lg, keyB0);
      FRAG8(b1, Bs + (wc * 64 + 32 + l31) * 128, tt, lg, keyB1);
      acc00 = __builtin_amdgcn_mfma_scale_f32_32x32x64_f8f6f4(a0, b0, acc00, 0, 0, 0, SCALE1, 0, SCALE1);
      acc01 = __builtin_amdgcn_mfma_scale_f32_32x32x64_f8f6f4(a0, b1, acc01, 0, 0, 0, SCALE1, 0, SCALE1);
      acc10 = __builtin_amdgcn_mfma_scale_f32_32x32x64_f8f6f4(a1, b0, acc10, 0, 0, 0, SCALE1, 0, SCALE1);
      acc11 = __builtin_amdgcn_mfma_scale_f32_32x32x64_f8f6f4(a1, b1, acc11, 0, 0, 0, SCALE1, 0, SCALE1);
    }
    __syncthreads();
  }

  // ---------------- epilogue: approx min + exact rescore ----------------
  float cnv0 = cn[k0 + wc * 64 + l31];
  float cnv1 = cn[k0 + wc * 64 + 32 + l31];

  EPILOG_M(acc00, acc01, 0);
  EPILOG_M(acc10, acc11, 32);
}

// ============================ fp32 fallback path ============================

__global__ void cnorm_kernel(const float* __restrict__ C, float* __restrict__ cnorm,
                             int D, int K) {
  int k = blockIdx.x * blockDim.x + threadIdx.x;
  if (k >= K) return;
  float s = 0.f;
  for (int d = 0; d < D; ++d) {
    float v = C[(size_t)d * K + k];
    s = fmaf(v, v, s);
  }
  cnorm[k] = s;
}

__global__ void init_kernel(u64* best, int N) {
  int n = blockIdx.x * blockDim.x + threadIdx.x;
  if (n < N) best[n] = ~0ULL;
}

__global__ __launch_bounds__(256) void assign_kernel(
    const float* __restrict__ X, const float* __restrict__ C,
    const float* __restrict__ cnorm, u64* __restrict__ best,
    int N, int D, int K) {
  __shared__ float Xs[16][128];
  __shared__ float Cs[16][64];
  const int t = threadIdx.x;
  const int tx = t & 15, ty = t >> 4;
  const int k0 = blockIdx.x * 64;
  const int n0 = blockIdx.y * 128;
  float acc[8][4];
#pragma unroll
  for (int i = 0; i < 8; ++i)
#pragma unroll
    for (int j = 0; j < 4; ++j) acc[i][j] = 0.f;
  for (int d0 = 0; d0 < D; d0 += 16) {
#pragma unroll
    for (int v = 0; v < 2; ++v) {
      int f4 = t + v * 256;
      int row = f4 >> 2;
      int dc = (f4 & 3) * 4;
      const float4 xv = *(const float4*)&X[(size_t)(n0 + row) * D + d0 + dc];
      Xs[dc + 0][row] = xv.x; Xs[dc + 1][row] = xv.y;
      Xs[dc + 2][row] = xv.z; Xs[dc + 3][row] = xv.w;
    }
    {
      int d = t >> 4, kc = (t & 15) * 4, k = k0 + kc;
      float4 cv;
      if (k + 3 < K) cv = *(const float4*)&C[(size_t)(d0 + d) * K + k];
      else {
        cv.x = (k + 0 < K) ? C[(size_t)(d0 + d) * K + k + 0] : 0.f;
        cv.y = (k + 1 < K) ? C[(size_t)(d0 + d) * K + k + 1] : 0.f;
        cv.z = (k + 2 < K) ? C[(size_t)(d0 + d) * K + k + 2] : 0.f;
        cv.w = (k + 3 < K) ? C[(size_t)(d0 + d) * K + k + 3] : 0.f;
      }
      *(float4*)&Cs[d][kc] = cv;
    }
    __syncthreads();
#pragma unroll
    for (int d = 0; d < 16; ++d) {
      float4 a0 = *(const float4*)&Xs[d][ty * 8];
      float4 a1 = *(const float4*)&Xs[d][ty * 8 + 4];
      float4 b = *(const float4*)&Cs[d][tx * 4];
      float av[8] = {a0.x, a0.y, a0.z, a0.w, a1.x, a1.y, a1.z, a1.w};
      float bv[4] = {b.x, b.y, b.z, b.w};
#pragma unroll
      for (int i = 0; i < 8; ++i)
#pragma unroll
        for (int j = 0; j < 4; ++j) acc[i][j] = fmaf(av[i], bv[j], acc[i][j]);
    }
    __syncthreads();
  }
  float cnv[4];
#pragma unroll
  for (int j = 0; j < 4; ++j) {
    int k = k0 + tx * 4 + j;
    cnv[j] = (k < K) ? cnorm[k] : 0.f;
  }
#pragma unroll
  for (int i = 0; i < 8; ++i) {
    u64 key = ~0ULL;
#pragma unroll
    for (int j = 0; j < 4; ++j) {
      int k = k0 + tx * 4 + j;
      if (k < K) {
        float score = fmaf(-2.f, acc[i][j], cnv[j]);
        u64 cand = ((u64)fsort(score) << 32) | (unsigned)k;
        key = key < cand ? key : cand;
      }
    }
#pragma unroll
    for (int mk = 8; mk >= 1; mk >>= 1) {
      u64 other = __shfl_xor(key, mk, 16);
      key = key < other ? key : other;
    }
    if (tx == 0) atomicMin(&best[n0 + ty * 8 + i], key);
  }
}

// ---------------- shared output kernel ----------------
__global__ void out_kernel(const u64* __restrict__ best, int* __restrict__ out, int N) {
  int n = blockIdx.x * blockDim.x + threadIdx.x;
  if (n < N) out[n] = (int)(u32)(best[n] & 0xffffffffu);
}

extern "C" void kernel_launch(void* const* d_in, const int* in_sizes, int n_in,
                              void* d_out, int out_size, void* d_ws, size_t ws_size,
                              hipStream_t stream) {
  const float* X = (const float*)d_in[0];  // [N, D]
  const float* C = (const float*)d_in[1];  // [D, K]
  int* out = (int*)d_out;

  // ws layout: best | amin | cnorm | Xq | Cq | Ct
  const size_t OFF_BEST = 0;
  const size_t OFF_AMIN = 131072;
  const size_t OFF_CN   = 196608;
  const size_t OFF_XQ   = 262144;
  const size_t OFF_CQ   = OFF_XQ + (size_t)N_ROWS * DDIM;         // 12845056
  const size_t OFF_CT   = OFF_CQ + (size_t)KPAD * DDIM;           // 20611072
  const size_t REQ_A    = OFF_CT + (size_t)KPAD * DDIM * 4;       // 51675136

  if (ws_size >= REQ_A) {
    u64* best = (u64*)((char*)d_ws + OFF_BEST);
    u32* amin = (u32*)((char*)d_ws + OFF_AMIN);
    float* cnp = (float*)((char*)d_ws + OFF_CN);
    unsigned char* Xq = (unsigned char*)((char*)d_ws + OFF_XQ);
    unsigned char* Cq = (unsigned char*)((char*)d_ws + OFF_CQ);
    float* Ct = (float*)((char*)d_ws + OFF_CT);

    hipLaunchKernelGGL(prep_kernel, dim3(TRANSC_BLKS + CONVX_BLKS + CNORM_BLKS), dim3(256),
                       0, stream, X, C, Xq, Cq, Ct, cnp, best);
    hipLaunchKernelGGL(seed_fp8, dim3(N_ROWS / 128), dim3(256), 0, stream, Xq, Cq, cnp, amin);
    hipLaunchKernelGGL(assign_fp8, dim3(N_ROWS / 128, KPAD / 128), dim3(256), 0, stream,
                       Xq, Cq, X, Ct, cnp, amin, best);
    hipLaunchKernelGGL(out_kernel, dim3(64), dim3(256), 0, stream, best, out, N_ROWS);
  } else {
    // fp32 fallback (round-2 passing path)
    u64* best = (u64*)d_ws;
    float* cnorm = (float*)((char*)d_ws + (size_t)N_ROWS * sizeof(u64));
    hipLaunchKernelGGL(init_kernel, dim3(64), dim3(256), 0, stream, best, N_ROWS);
    hipLaunchKernelGGL(cnorm_kernel, dim3((KCOLS + 255) / 256), dim3(256), 0, stream,
                       C, cnorm, DDIM, KCOLS);
    hipLaunchKernelGGL(assign_kernel, dim3((KCOLS + 63) / 64, N_ROWS / 128), dim3(256), 0,
                       stream, X, C, cnorm, best, N_ROWS, DDIM, KCOLS);
    hipLaunchKernelGGL(out_kernel, dim3(64), dim3(256), 0, stream, best, out, N_ROWS);
  }
}